// Round 9
// baseline (137.614 us; speedup 1.0000x reference)
//
#include <hip/hip_runtime.h>
#include <math.h>

#define NCAM  6
#define INC   256
#define HH    56
#define WW    100
#define HW    5600
#define NPIX  33600
#define DDEP  41
#define CFEAT 64
#define NCH   105          // 41 depth + 64 feat
#define NXG   33
#define NYG   33
#define NZG   2
#define NVOX  2178         // 2*33*33
#define PADW  35
#define PADHW 1225         // 35*35
#define NPIXO 1089         // 33*33

typedef short bf16x8 __attribute__((ext_vector_type(8)));
typedef float f32x4  __attribute__((ext_vector_type(4)));

// ---- workspace layout (floats); ws ~268 MB so no aliasing needed ----------
#define Y_OFF    0
#define Y_SZ     (NCAM * NCH * HW)          // 3,528,000
#define WDH_OFF  (Y_OFF + Y_SZ)             // dn weights: 128*256 shorts = 16384 fl
#define WDL_OFF  (WDH_OFF + 16384)
#define W1H_OFF  (WDL_OFF + 16384)          // 9*128*128 shorts = 73,728 fl
#define W1L_OFF  (W1H_OFF + 73728)
#define W2H_OFF  (W1L_OFF + 73728)          // 9*512*128 shorts = 294,912 fl
#define W2L_OFF  (W2H_OFF + 294912)
#define W3H_OFF  (W2L_OFF + 294912)         // 9*512*512 shorts = 1,179,648 fl
#define W3L_OFF  (W3H_OFF + 1179648)
#define W4H_OFF  (W3L_OFF + 1179648)        // 9*256*512 shorts = 589,824 fl
#define W4L_OFF  (W4H_OFF + 589824)
#define BEV_OFF  (W4L_OFF + 589824)
#define BEV_SZ   (NVOX * CFEAT)             // 139,392
#define A0H_OFF  (BEV_OFF + BEV_SZ)         // acts: [1225][CIN] bf16 (hi/lo)
#define A0L_OFF  (A0H_OFF + 78400)
#define A1H_OFF  (A0L_OFF + 78400)
#define A1L_OFF  (A1H_OFF + 78400)
#define A2H_OFF  (A1L_OFF + 78400)          // 1225*512 shorts = 313,600 fl
#define A2L_OFF  (A2H_OFF + 313600)
#define A3H_OFF  (A2L_OFF + 313600)
#define A3L_OFF  (A3H_OFF + 313600)
#define P_OFF    (A3L_OFF + 313600)
#define P_SZ     4460544                    // max slices*1089*COUT (8*1089*512)
#define WS_END   (P_OFF + P_SZ)             // ~56 MB

__device__ __forceinline__ unsigned short f2bf_rn(float f) {
    unsigned u = __builtin_bit_cast(unsigned, f);
    unsigned r = (u + 0x7FFFu + ((u >> 16) & 1u)) >> 16;
    return (unsigned short)r;
}
__device__ __forceinline__ void split_bf(float f, unsigned short& h, unsigned short& l) {
    h = f2bf_rn(f);
    float hf = __builtin_bit_cast(float, (unsigned)h << 16);
    l = f2bf_rn(f - hf);
}
// cheap truncation split (hot path): err 2^-16 rel vs 2^-17 for rn — fine.
__device__ __forceinline__ void split_bf_trunc(float f, short& h, short& l) {
    unsigned u = __builtin_bit_cast(unsigned, f);
    h = (short)(u >> 16);
    float hf = __builtin_bit_cast(float, u & 0xFFFF0000u);
    float r = f - hf;
    l = (short)(__builtin_bit_cast(unsigned, r) >> 16);
}

// ---------------- unified weight prep (dn + 4 convs), fragment layout ------
__device__ __forceinline__ void wprep_conv(const float* __restrict__ wgt,
                                           unsigned short* __restrict__ wh,
                                           unsigned short* __restrict__ wl,
                                           int COUT, int CIN, int i)
{
    int jj = i & 7, lane = (i >> 3) & 63;
    int r  = i >> 9;
    int nchk = CIN >> 5;
    int chk = r % nchk; r /= nchk;
    int ncog = COUT >> 4;
    int cog = r % ncog; int dydx = r / ncog;
    int co = cog * 16 + (lane & 15);
    int ci = chk * 32 + (lane >> 4) * 8 + jj;
    float w = wgt[((size_t)co * CIN + ci) * 9 + dydx];
    unsigned short h, l; split_bf(w, h, l);
    wh[i] = h; wl[i] = l;
}

__global__ __launch_bounds__(256) void k_wprep_all(const float* __restrict__ dnw,
                                                   const float* __restrict__ bw1,
                                                   const float* __restrict__ bw2,
                                                   const float* __restrict__ bw3,
                                                   const float* __restrict__ bw4,
                                                   unsigned short* __restrict__ wdh,
                                                   unsigned short* __restrict__ wdl,
                                                   unsigned short* __restrict__ w1h,
                                                   unsigned short* __restrict__ w1l,
                                                   unsigned short* __restrict__ w2h,
                                                   unsigned short* __restrict__ w2l,
                                                   unsigned short* __restrict__ w3h,
                                                   unsigned short* __restrict__ w3l,
                                                   unsigned short* __restrict__ w4h,
                                                   unsigned short* __restrict__ w4l)
{
    int i = blockIdx.x * 256 + threadIdx.x;
    if (i < 32768) {   // depthnet [ct][chk][lane][jj]
        int jj = i & 7, lane = (i >> 3) & 63, chk = (i >> 9) & 7, ct = i >> 12;
        int co = ct * 16 + (lane & 15);
        int ci = chk * 32 + (lane >> 4) * 8 + jj;
        float w = (co < NCH) ? dnw[co * 256 + ci] : 0.f;
        unsigned short h, l; split_bf(w, h, l);
        wdh[i] = h; wdl[i] = l;
        return;
    }
    i -= 32768;
    if (i < 147456)  { wprep_conv(bw1, w1h, w1l, 128, 128, i); return; }
    i -= 147456;
    if (i < 589824)  { wprep_conv(bw2, w2h, w2l, 512, 128, i); return; }
    i -= 589824;
    if (i < 2359296) { wprep_conv(bw3, w3h, w3l, 512, 512, i); return; }
    i -= 2359296;
    if (i < 1179648) { wprep_conv(bw4, w4h, w4l, 256, 512, i); return; }
}

// ---------------- Stage 1+2: depthnet MFMA (all 7 co-tiles) + softmax ------
// grid (88,6): x read/converted ONCE; 21 MFMA per 8 loads; trunc split.
__global__ __launch_bounds__(256) void k_depthnet_fused(const float* __restrict__ x,
                                                        const unsigned short* __restrict__ wdh,
                                                        const unsigned short* __restrict__ wdl,
                                                        const float* __restrict__ dnb,
                                                        float* __restrict__ y)
{
    const int t  = threadIdx.x;
    const int w  = t >> 6;
    const int l  = t & 63;
    const int lp = l & 15;
    const int q  = l >> 4;
    const int n   = blockIdx.y;
    const int px  = blockIdx.x * 64 + w * 16 + lp;
    const bool pok = px < HW;
    const float* xl = x + (size_t)n * INC * HW + (pok ? px : 0);

    f32x4 acc[7];
#pragma unroll
    for (int ct = 0; ct < 7; ++ct) acc[ct] = (f32x4){0.f, 0.f, 0.f, 0.f};

#pragma unroll 2
    for (int ci0 = 0; ci0 < INC; ci0 += 32) {
        float bv[8];
#pragma unroll
        for (int jj = 0; jj < 8; ++jj)
            bv[jj] = xl[(size_t)(ci0 + q * 8 + jj) * HW];
        bf16x8 Bh, Bl;
#pragma unroll
        for (int jj = 0; jj < 8; ++jj) {
            short h, lo; split_bf_trunc(pok ? bv[jj] : 0.f, h, lo);
            Bh[jj] = h; Bl[jj] = lo;
        }
#pragma unroll
        for (int ct = 0; ct < 7; ++ct) {
            const size_t ab = (size_t)((ct * 8 + (ci0 >> 5)) * 64 + l) * 8;
            bf16x8 Ah = *(const bf16x8*)&wdh[ab];
            bf16x8 Al = *(const bf16x8*)&wdl[ab];
            acc[ct] = __builtin_amdgcn_mfma_f32_16x16x32_bf16(Ah, Bh, acc[ct], 0, 0, 0);
            acc[ct] = __builtin_amdgcn_mfma_f32_16x16x32_bf16(Ah, Bl, acc[ct], 0, 0, 0);
            acc[ct] = __builtin_amdgcn_mfma_f32_16x16x32_bf16(Al, Bh, acc[ct], 0, 0, 0);
        }
    }

    // bias for softmax tiles (ct 0..3 cover co 0..63 >= all 41 depth ch)
    float v[4][4];
#pragma unroll
    for (int ct = 0; ct < 4; ++ct)
#pragma unroll
        for (int j = 0; j < 4; ++j) {
            int co = ct * 16 + q * 4 + j;
            v[ct][j] = acc[ct][j] + dnb[co];
        }

    // fused softmax across the 4 lanes sharing a px (lp, q=0..3)
    {
        float m = -3.4e38f;
#pragma unroll
        for (int ct = 0; ct < 4; ++ct)
#pragma unroll
            for (int j = 0; j < 4; ++j) {
                int co = ct * 16 + q * 4 + j;
                if (co < DDEP) m = fmaxf(m, v[ct][j]);
            }
        m = fmaxf(m, __shfl_xor(m, 16));
        m = fmaxf(m, __shfl_xor(m, 32));
        float s = 0.f;
        float e[4][4];
#pragma unroll
        for (int ct = 0; ct < 4; ++ct)
#pragma unroll
            for (int j = 0; j < 4; ++j) {
                int co = ct * 16 + q * 4 + j;
                e[ct][j] = (co < DDEP) ? expf(v[ct][j] - m) : 0.f;
                s += e[ct][j];
            }
        s += __shfl_xor(s, 16);
        s += __shfl_xor(s, 32);
#pragma unroll
        for (int ct = 0; ct < 4; ++ct)
#pragma unroll
            for (int j = 0; j < 4; ++j) {
                int co = ct * 16 + q * 4 + j;
                if (co < DDEP) v[ct][j] = e[ct][j] / s;
            }
    }

    if (pok) {
#pragma unroll
        for (int ct = 0; ct < 4; ++ct)
#pragma unroll
            for (int j = 0; j < 4; ++j) {
                int co = ct * 16 + q * 4 + j;
                y[((size_t)n * NCH + co) * HW + px] = v[ct][j];
            }
#pragma unroll
        for (int ct = 4; ct < 7; ++ct)
#pragma unroll
            for (int j = 0; j < 4; ++j) {
                int co = ct * 16 + q * 4 + j;
                if (co < NCH)
                    y[((size_t)n * NCH + co) * HW + px] = acc[ct][j] + dnb[co];
            }
    }
}

// ---------------- Stage 3: splat with LDS voxel cache + run-length dedup ---
__global__ __launch_bounds__(256) void k_splat2(const float* __restrict__ y,
                                                const float* __restrict__ rots,
                                                const float* __restrict__ trans,
                                                float* __restrict__ bev)
{
    __shared__ int vox[32 * DDEP];
    const int t  = threadIdx.x;
    const int p0 = blockIdx.x * 32;

    for (int k = t; k < 32 * DDEP; k += 256) {
        int pl = k / DDEP, d = k - pl * DDEP;
        int p = p0 + pl;
        int vx = -1;
        {
            int n = p / HW, hw = p - n * HW;
            int wi = hw % WW, hi = hw / WW;
            const float su = 1599.0f / 99.0f;
            const float sv = 899.0f / 55.0f;
            float u = __fmul_rn((float)wi, su);
            float v = __fmul_rn((float)hi, sv);
            const float* r = rots + n * 9;
            const float* tr = trans + n * 3;
            float dd  = 4.0f + (float)d;
            float pxv = __fmul_rn(u, dd);
            float pyv = __fmul_rn(v, dd);
            float gx = __fadd_rn(__fadd_rn(__fadd_rn(__fmul_rn(r[0], pxv), __fmul_rn(r[1], pyv)), __fmul_rn(r[2], dd)), tr[0]);
            float gy = __fadd_rn(__fadd_rn(__fadd_rn(__fmul_rn(r[3], pxv), __fmul_rn(r[4], pyv)), __fmul_rn(r[5], dd)), tr[1]);
            float gz = __fadd_rn(__fadd_rn(__fadd_rn(__fmul_rn(r[6], pxv), __fmul_rn(r[7], pyv)), __fmul_rn(r[8], dd)), tr[2]);
            int cx = (int)__fdiv_rn(__fadd_rn(gx, 50.0f), 3.0f);
            int cy = (int)__fdiv_rn(__fadd_rn(gy, 50.0f), 3.0f);
            int cz = (int)__fdiv_rn(__fadd_rn(gz, 5.0f), 3.0f);
            if (cx >= 0 && cx < NXG && cy >= 0 && cy < NYG && cz >= 0 && cz < NZG)
                vx = (cz * NYG + cy) * NXG + cx;
        }
        vox[k] = vx;
    }
    __syncthreads();

    const int g  = t >> 5;    // channel group 0..7
    const int pl = t & 31;
    const int p  = p0 + pl;
    int n = p / HW, hw = p - n * HW;
    const float* dbase = y + (size_t)n * NCH * HW + hw;
    const float* fbase = dbase + (size_t)DDEP * HW;
    float f[8];
#pragma unroll
    for (int j = 0; j < 8; ++j) f[j] = fbase[(size_t)(g * 8 + j) * HW];

    float a[8];
#pragma unroll
    for (int j = 0; j < 8; ++j) a[j] = 0.f;
    int cur = -1;
    for (int d = 0; d < DDEP; ++d) {
        int vx = vox[pl * DDEP + d];
        if (vx != cur) {
            if (cur >= 0) {
                float* vp = bev + (size_t)cur * CFEAT + g * 8;
#pragma unroll
                for (int j = 0; j < 8; ++j) atomicAdd(vp + j, a[j]);
            }
            cur = vx;
#pragma unroll
            for (int j = 0; j < 8; ++j) a[j] = 0.f;
        }
        if (vx >= 0) {
            float dval = dbase[(size_t)d * HW];
#pragma unroll
            for (int j = 0; j < 8; ++j) a[j] += __fmul_rn(dval, f[j]);
        }
    }
    if (cur >= 0) {
        float* vp = bev + (size_t)cur * CFEAT + g * 8;
#pragma unroll
        for (int j = 0; j < 8; ++j) atomicAdd(vp + j, a[j]);
    }
}

// ---------------- bev [vox][c] -> act0 transposed [1225][128] bf16 h/l -----
__global__ __launch_bounds__(256) void k_bev2act(const float* __restrict__ bev,
                                                 unsigned short* __restrict__ ah,
                                                 unsigned short* __restrict__ al)
{
    int i = blockIdx.x * 256 + threadIdx.x;
    if (i >= NVOX * CFEAT) return;
    int vx = i >> 6, c = i & 63;
    int cz = vx / NPIXO, rem = vx - cz * NPIXO;
    int yy = rem / NXG, xx = rem - yy * NXG;
    int ch = c * 2 + cz;
    int pos = (yy + 1) * PADW + xx + 1;
    unsigned short h, l; split_bf(bev[i], h, l);
    ah[pos * 128 + ch] = h;
    al[pos * 128 + ch] = l;
}

// ---------------- MFMA 3x3 conv partials, single-barrier full-K staging ----
// Stage ALL CI_PER channels (CHUNKS*8 slots/pos, 16-slot XOR swizzle), one
// __syncthreads, then 135*CHUNKS contiguous MFMAs per wave.
template<int CIN, int COUT, int SL>
__global__ __launch_bounds__(256) void k_conv_mfma(const unsigned short* __restrict__ ah,
                                                   const unsigned short* __restrict__ al,
                                                   const unsigned short* __restrict__ wh,
                                                   const unsigned short* __restrict__ wl,
                                                   float* __restrict__ P)
{
    constexpr int CI_PER = CIN / SL;
    constexpr int CHUNKS = CI_PER / 32;       // 1 or 2
    constexpr int NSLOT  = CHUNKS * 8;
    constexpr int SMASK  = NSLOT - 1;
    constexpr int ROW    = CHUNKS * 64;       // shorts per pos
    constexpr int NCOB = COUT / 64;
    constexpr int G    = NCOB * SL;
    constexpr int GX   = G / 8;
    constexpr int POSN = 140;
    __shared__ unsigned short bs[POSN * ROW]; // 17.9 or 35.8 KB
    const int t  = threadIdx.x;
    const int w  = t >> 6;
    const int l  = t & 63;
    const int lp = l & 15;
    const int q  = l >> 4;

    const int bid   = blockIdx.x;
    const int xcd   = bid & 7;
    const int slot  = bid >> 3;
    const int ytile = slot % 17;
    const int gon   = slot / 17;
    const int group = xcd * GX + gon;
    const int cobi  = group % NCOB;
    const int sl    = group / NCOB;

    const int y0  = ytile * 2;
    const int cob = cobi * 64 + w * 16;
    const int ci_base = sl * CI_PER;

    int  pos0[5];
    bool vld[5];
#pragma unroll
    for (int ct = 0; ct < 5; ++ct) {
        int tp = ct * 16 + lp;
        int r = tp / 33, c = tp - r * 33;
        bool v = (tp < 66) && (y0 + r < 33);
        vld[ct]  = v;
        pos0[ct] = v ? (r * 35 + c) : 0;
    }

    // stage all CI_PER channels, hi+lo, swizzled
    for (int i = t; i < POSN * NSLOT; i += 256) {
        int pos = i / NSLOT, s = i - pos * NSLOT;
        int gpos = y0 * 35 + pos;
        bool hi = s < CHUNKS * 4;
        int sq = hi ? s : s - CHUNKS * 4;
        int cio = (sq >> 2) * 32 + (sq & 3) * 8;
        const unsigned short* src = hi ? ah : al;
        int sp = s ^ (pos & SMASK);
        uint4 val = make_uint4(0u, 0u, 0u, 0u);
        if (gpos < PADHW)
            val = *(const uint4*)&src[(size_t)gpos * CIN + ci_base + cio];
        *(uint4*)&bs[pos * ROW + sp * 8] = val;
    }
    __syncthreads();

    f32x4 acc[5];
#pragma unroll
    for (int ct = 0; ct < 5; ++ct) acc[ct] = (f32x4){0.f, 0.f, 0.f, 0.f};

#pragma unroll 3
    for (int dydx = 0; dydx < 9; ++dydx) {
        int dy = dydx / 3, dx = dydx - dy * 3;
        int off = dy * 35 + dx;
        bf16x8 Ah[CHUNKS], Al[CHUNKS];
#pragma unroll
        for (int c = 0; c < CHUNKS; ++c) {
            const size_t abase = (size_t)(((dydx * (COUT >> 4) + (cob >> 4)) * (CIN >> 5)
                                           + (ci_base >> 5) + c) * 64 + l) * 8;
            Ah[c] = *(const bf16x8*)&wh[abase];
            Al[c] = *(const bf16x8*)&wl[abase];
        }
#pragma unroll
        for (int ct = 0; ct < 5; ++ct) {
            int pos = pos0[ct] + off;
#pragma unroll
            for (int c = 0; c < CHUNKS; ++c) {
                int sph = (c * 4 + q) ^ (pos & SMASK);
                bf16x8 Bh = *(const bf16x8*)&bs[pos * ROW + sph * 8];
                bf16x8 Bl = *(const bf16x8*)&bs[pos * ROW + (sph ^ (CHUNKS * 4)) * 8];
                acc[ct] = __builtin_amdgcn_mfma_f32_16x16x32_bf16(Ah[c], Bh, acc[ct], 0, 0, 0);
                acc[ct] = __builtin_amdgcn_mfma_f32_16x16x32_bf16(Ah[c], Bl, acc[ct], 0, 0, 0);
                acc[ct] = __builtin_amdgcn_mfma_f32_16x16x32_bf16(Al[c], Bh, acc[ct], 0, 0, 0);
            }
        }
    }

#pragma unroll
    for (int ct = 0; ct < 5; ++ct) {
        if (!vld[ct]) continue;
        int gp = y0 * 33 + ct * 16 + lp;
        float* dst = P + ((size_t)sl * NPIXO + gp) * COUT + cob + q * 4;
        *(f32x4*)dst = acc[ct];
    }
}

// ---------------- reduce slices + BN + ReLU -> next act (or final out) -----
template<int SL>
__global__ __launch_bounds__(256) void k_finish(const float* __restrict__ P,
                                                const float* __restrict__ bns,
                                                const float* __restrict__ bnb,
                                                const float* __restrict__ bnm,
                                                const float* __restrict__ bnv,
                                                unsigned short* __restrict__ oh,
                                                unsigned short* __restrict__ ol,
                                                float* __restrict__ outf,
                                                int COUT)
{
    int i = blockIdx.x * 256 + threadIdx.x;
    if (i >= COUT * NPIXO) return;
    int co = i % COUT, p = i / COUT;
    float s = 0.f;
#pragma unroll
    for (int sl = 0; sl < SL; ++sl)
        s += P[((size_t)sl * NPIXO + p) * COUT + co];
    float sc = bns[co] / sqrtf(bnv[co] + 1e-5f);
    float bi = bnb[co] - bnm[co] * sc;
    float rv = fmaxf(fmaf(s, sc, bi), 0.f);
    if (outf) {
        outf[(size_t)co * NPIXO + p] = rv;
    } else {
        int yy = p / NXG, xx = p - yy * NXG;
        int pos = (yy + 1) * PADW + xx + 1;
        unsigned short h, lo; split_bf(rv, h, lo);
        oh[(size_t)pos * COUT + co] = h;
        ol[(size_t)pos * COUT + co] = lo;
    }
}

extern "C" void kernel_launch(void* const* d_in, const int* in_sizes, int n_in,
                              void* d_out, int out_size, void* d_ws, size_t ws_size,
                              hipStream_t stream)
{
    const float* x     = (const float*)d_in[0];
    const float* rots  = (const float*)d_in[1];
    const float* trans = (const float*)d_in[2];
    const float* dnw   = (const float*)d_in[3];
    const float* dnb   = (const float*)d_in[4];
    const float* bw1   = (const float*)d_in[5];
    const float* bn1s  = (const float*)d_in[6];
    const float* bn1b  = (const float*)d_in[7];
    const float* bn1m  = (const float*)d_in[8];
    const float* bn1v  = (const float*)d_in[9];
    const float* bw2   = (const float*)d_in[10];
    const float* bn2s  = (const float*)d_in[11];
    const float* bn2b  = (const float*)d_in[12];
    const float* bn2m  = (const float*)d_in[13];
    const float* bn2v  = (const float*)d_in[14];
    const float* bw3   = (const float*)d_in[15];
    const float* bn3s  = (const float*)d_in[16];
    const float* bn3b  = (const float*)d_in[17];
    const float* bn3m  = (const float*)d_in[18];
    const float* bn3v  = (const float*)d_in[19];
    const float* bw4   = (const float*)d_in[20];
    const float* bn4s  = (const float*)d_in[21];
    const float* bn4b  = (const float*)d_in[22];
    const float* bn4m  = (const float*)d_in[23];
    const float* bn4v  = (const float*)d_in[24];

    float* ws  = (float*)d_ws;
    float* y   = ws + Y_OFF;
    float* bev = ws + BEV_OFF;
    float* P   = ws + P_OFF;
    unsigned short* wdh = (unsigned short*)(ws + WDH_OFF);
    unsigned short* wdl = (unsigned short*)(ws + WDL_OFF);
    unsigned short* w1h = (unsigned short*)(ws + W1H_OFF);
    unsigned short* w1l = (unsigned short*)(ws + W1L_OFF);
    unsigned short* w2h = (unsigned short*)(ws + W2H_OFF);
    unsigned short* w2l = (unsigned short*)(ws + W2L_OFF);
    unsigned short* w3h = (unsigned short*)(ws + W3H_OFF);
    unsigned short* w3l = (unsigned short*)(ws + W3L_OFF);
    unsigned short* w4h = (unsigned short*)(ws + W4H_OFF);
    unsigned short* w4l = (unsigned short*)(ws + W4L_OFF);
    unsigned short* a0h = (unsigned short*)(ws + A0H_OFF);
    unsigned short* a0l = (unsigned short*)(ws + A0L_OFF);
    unsigned short* a1h = (unsigned short*)(ws + A1H_OFF);
    unsigned short* a1l = (unsigned short*)(ws + A1L_OFF);
    unsigned short* a2h = (unsigned short*)(ws + A2H_OFF);
    unsigned short* a2l = (unsigned short*)(ws + A2L_OFF);
    unsigned short* a3h = (unsigned short*)(ws + A3H_OFF);
    unsigned short* a3l = (unsigned short*)(ws + A3L_OFF);
    float* out = (float*)d_out;

    // zero bev accumulator + act buffers (their padded borders must be 0)
    hipMemsetAsync(bev, 0, (size_t)(P_OFF - BEV_OFF) * sizeof(float), stream);

    k_wprep_all<<<16832, 256, 0, stream>>>(dnw, bw1, bw2, bw3, bw4,
                                           wdh, wdl, w1h, w1l, w2h, w2l,
                                           w3h, w3l, w4h, w4l);
    // depthnet + fused softmax (x read once, 528 blocks)
    k_depthnet_fused<<<dim3(88, 6), 256, 0, stream>>>(x, wdh, wdl, dnb, y);
    // splat with voxel dedup
    k_splat2<<<1050, 256, 0, stream>>>(y, rots, trans, bev);

    k_bev2act<<<(NVOX * CFEAT + 255) / 256, 256, 0, stream>>>(bev, a0h, a0l);

    // conv1: 128 -> 128   (136 blocks)
    k_conv_mfma<128, 128, 4><<<136, 256, 0, stream>>>(a0h, a0l, w1h, w1l, P);
    k_finish<4><<<(128 * NPIXO + 255) / 256, 256, 0, stream>>>(P, bn1s, bn1b, bn1m, bn1v, a1h, a1l, nullptr, 128);
    // conv2: 128 -> 512   (544 blocks)
    k_conv_mfma<128, 512, 4><<<544, 256, 0, stream>>>(a1h, a1l, w2h, w2l, P);
    k_finish<4><<<(512 * NPIXO + 255) / 256, 256, 0, stream>>>(P, bn2s, bn2b, bn2m, bn2v, a2h, a2l, nullptr, 512);
    // conv3: 512 -> 512, SL=8  (1088 blocks, single-barrier 64-ci staging)
    k_conv_mfma<512, 512, 8><<<1088, 256, 0, stream>>>(a2h, a2l, w3h, w3l, P);
    k_finish<8><<<(512 * NPIXO + 255) / 256, 256, 0, stream>>>(P, bn3s, bn3b, bn3m, bn3v, a3h, a3l, nullptr, 512);
    // conv4: 512 -> 256, SL=8  (544 blocks)
    k_conv_mfma<512, 256, 8><<<544, 256, 0, stream>>>(a3h, a3l, w4h, w4l, P);
    k_finish<8><<<(256 * NPIXO + 255) / 256, 256, 0, stream>>>(P, bn4s, bn4b, bn4m, bn4v, nullptr, nullptr, out, 256);
}

// Round 10
// 118.328 us; speedup vs baseline: 1.1630x; 1.1630x over previous
//
#include <hip/hip_runtime.h>
#include <math.h>

#define NCAM  6
#define INC   256
#define HH    56
#define WW    100
#define HW    5600
#define NPIX  33600
#define DDEP  41
#define CFEAT 64
#define NCH   105          // 41 depth + 64 feat
#define NXG   33
#define NYG   33
#define NZG   2
#define NVOX  2178         // 2*33*33
#define PADW  35
#define PADHW 1225         // 35*35
#define NPIXO 1089         // 33*33

typedef short bf16x8 __attribute__((ext_vector_type(8)));
typedef float f32x4  __attribute__((ext_vector_type(4)));

// ---- workspace layout (floats); ws ~268 MB so no aliasing needed ----------
#define Y_OFF    0
#define Y_SZ     (NCAM * NCH * HW)          // 3,528,000
#define WDH_OFF  (Y_OFF + Y_SZ)             // dn weights: 128*256 shorts
#define WDL_OFF  (WDH_OFF + 16384)
#define W1H_OFF  (WDL_OFF + 16384)          // 9*128*128 shorts = 73,728 fl
#define W1L_OFF  (W1H_OFF + 73728)
#define W2H_OFF  (W1L_OFF + 73728)          // 9*512*128 shorts = 294,912 fl
#define W2L_OFF  (W2H_OFF + 294912)
#define W3H_OFF  (W2L_OFF + 294912)         // 9*512*512 shorts = 1,179,648 fl
#define W3L_OFF  (W3H_OFF + 1179648)
#define W4H_OFF  (W3L_OFF + 1179648)        // 9*256*512 shorts = 589,824 fl
#define W4L_OFF  (W4H_OFF + 589824)
#define BEV_OFF  (W4L_OFF + 589824)
#define BEV_SZ   (NVOX * CFEAT)             // 139,392
// acts: SINGLE bf16 [1225][CIN]
#define A0_OFF   (BEV_OFF + BEV_SZ)         // 1225*128 shorts = 78,400 fl
#define A1_OFF   (A0_OFF + 78400)
#define A2_OFF   (A1_OFF + 78400)           // 1225*512 shorts = 313,600 fl
#define A3_OFF   (A2_OFF + 313600)
#define P_OFF    (A3_OFF + 313600)
#define P_SZ     4460544                    // max slices*1089*COUT (8*1089*512)
#define WS_END   (P_OFF + P_SZ)

__device__ __forceinline__ unsigned short f2bf_rn(float f) {
    unsigned u = __builtin_bit_cast(unsigned, f);
    unsigned r = (u + 0x7FFFu + ((u >> 16) & 1u)) >> 16;
    return (unsigned short)r;
}
__device__ __forceinline__ void split_bf(float f, unsigned short& h, unsigned short& l) {
    h = f2bf_rn(f);
    float hf = __builtin_bit_cast(float, (unsigned)h << 16);
    l = f2bf_rn(f - hf);
}
// cheap truncation split (hot path): err 2^-16 rel vs 2^-17 for rn — fine.
__device__ __forceinline__ void split_bf_trunc(float f, short& h, short& l) {
    unsigned u = __builtin_bit_cast(unsigned, f);
    h = (short)(u >> 16);
    float hf = __builtin_bit_cast(float, u & 0xFFFF0000u);
    float r = f - hf;
    l = (short)(__builtin_bit_cast(unsigned, r) >> 16);
}

// ---------------- unified weight prep (dn + 4 convs), fragment layout ------
__device__ __forceinline__ void wprep_conv(const float* __restrict__ wgt,
                                           unsigned short* __restrict__ wh,
                                           unsigned short* __restrict__ wl,
                                           int COUT, int CIN, int i)
{
    int jj = i & 7, lane = (i >> 3) & 63;
    int r  = i >> 9;
    int nchk = CIN >> 5;
    int chk = r % nchk; r /= nchk;
    int ncog = COUT >> 4;
    int cog = r % ncog; int dydx = r / ncog;
    int co = cog * 16 + (lane & 15);
    int ci = chk * 32 + (lane >> 4) * 8 + jj;
    float w = wgt[((size_t)co * CIN + ci) * 9 + dydx];
    unsigned short h, l; split_bf(w, h, l);
    wh[i] = h; wl[i] = l;
}

__global__ __launch_bounds__(256) void k_wprep_all(const float* __restrict__ dnw,
                                                   const float* __restrict__ bw1,
                                                   const float* __restrict__ bw2,
                                                   const float* __restrict__ bw3,
                                                   const float* __restrict__ bw4,
                                                   unsigned short* __restrict__ wdh,
                                                   unsigned short* __restrict__ wdl,
                                                   unsigned short* __restrict__ w1h,
                                                   unsigned short* __restrict__ w1l,
                                                   unsigned short* __restrict__ w2h,
                                                   unsigned short* __restrict__ w2l,
                                                   unsigned short* __restrict__ w3h,
                                                   unsigned short* __restrict__ w3l,
                                                   unsigned short* __restrict__ w4h,
                                                   unsigned short* __restrict__ w4l)
{
    int i = blockIdx.x * 256 + threadIdx.x;
    if (i < 32768) {   // depthnet [ct][chk][lane][jj]
        int jj = i & 7, lane = (i >> 3) & 63, chk = (i >> 9) & 7, ct = i >> 12;
        int co = ct * 16 + (lane & 15);
        int ci = chk * 32 + (lane >> 4) * 8 + jj;
        float w = (co < NCH) ? dnw[co * 256 + ci] : 0.f;
        unsigned short h, l; split_bf(w, h, l);
        wdh[i] = h; wdl[i] = l;
        return;
    }
    i -= 32768;
    if (i < 147456)  { wprep_conv(bw1, w1h, w1l, 128, 128, i); return; }
    i -= 147456;
    if (i < 589824)  { wprep_conv(bw2, w2h, w2l, 512, 128, i); return; }
    i -= 589824;
    if (i < 2359296) { wprep_conv(bw3, w3h, w3l, 512, 512, i); return; }
    i -= 2359296;
    if (i < 1179648) { wprep_conv(bw4, w4h, w4l, 256, 512, i); return; }
}

// ---------------- Stage 1+2: depthnet MFMA + fused softmax epilogue --------
// grid (88,6,2): z=0 owns co 0..63 (all 41 depth ch) -> in-register softmax;
// z=1 owns co 64..104.  3-term split (x truncation split, err 2^-16).
__global__ __launch_bounds__(256) void k_depthnet_fused(const float* __restrict__ x,
                                                        const unsigned short* __restrict__ wdh,
                                                        const unsigned short* __restrict__ wdl,
                                                        const float* __restrict__ dnb,
                                                        float* __restrict__ y)
{
    const int t  = threadIdx.x;
    const int w  = t >> 6;
    const int l  = t & 63;
    const int lp = l & 15;
    const int q  = l >> 4;
    const int n   = blockIdx.y;
    const int ct0 = blockIdx.z * 4;
    const int px  = blockIdx.x * 64 + w * 16 + lp;
    const bool pok = px < HW;
    const float* xl = x + (size_t)n * INC * HW + (pok ? px : 0);

    f32x4 acc[4];
#pragma unroll
    for (int ct = 0; ct < 4; ++ct) acc[ct] = (f32x4){0.f, 0.f, 0.f, 0.f};

#pragma unroll 2
    for (int ci0 = 0; ci0 < INC; ci0 += 32) {
        float bv[8];
#pragma unroll
        for (int jj = 0; jj < 8; ++jj)
            bv[jj] = xl[(size_t)(ci0 + q * 8 + jj) * HW];
        bf16x8 Bh, Bl;
#pragma unroll
        for (int jj = 0; jj < 8; ++jj) {
            short h, lo; split_bf_trunc(pok ? bv[jj] : 0.f, h, lo);
            Bh[jj] = h; Bl[jj] = lo;
        }
#pragma unroll
        for (int ct = 0; ct < 4; ++ct) {
            const size_t ab = (size_t)(((ct0 + ct) * 8 + (ci0 >> 5)) * 64 + l) * 8;
            bf16x8 Ah = *(const bf16x8*)&wdh[ab];
            bf16x8 Al = *(const bf16x8*)&wdl[ab];
            acc[ct] = __builtin_amdgcn_mfma_f32_16x16x32_bf16(Ah, Bh, acc[ct], 0, 0, 0);
            acc[ct] = __builtin_amdgcn_mfma_f32_16x16x32_bf16(Ah, Bl, acc[ct], 0, 0, 0);
            acc[ct] = __builtin_amdgcn_mfma_f32_16x16x32_bf16(Al, Bh, acc[ct], 0, 0, 0);
        }
    }

    float v[4][4];
#pragma unroll
    for (int ct = 0; ct < 4; ++ct)
#pragma unroll
        for (int j = 0; j < 4; ++j) {
            int co = (ct0 + ct) * 16 + q * 4 + j;
            v[ct][j] = acc[ct][j] + ((co < NCH) ? dnb[co] : 0.f);
        }

    if (ct0 == 0) {   // fused softmax over depth channels
        float m = -3.4e38f;
#pragma unroll
        for (int ct = 0; ct < 4; ++ct)
#pragma unroll
            for (int j = 0; j < 4; ++j) {
                int co = ct * 16 + q * 4 + j;
                if (co < DDEP) m = fmaxf(m, v[ct][j]);
            }
        m = fmaxf(m, __shfl_xor(m, 16));
        m = fmaxf(m, __shfl_xor(m, 32));
        float e[4][4];
        float s = 0.f;
#pragma unroll
        for (int ct = 0; ct < 4; ++ct)
#pragma unroll
            for (int j = 0; j < 4; ++j) {
                int co = ct * 16 + q * 4 + j;
                e[ct][j] = (co < DDEP) ? expf(v[ct][j] - m) : 0.f;
                s += e[ct][j];
            }
        s += __shfl_xor(s, 16);
        s += __shfl_xor(s, 32);
#pragma unroll
        for (int ct = 0; ct < 4; ++ct)
#pragma unroll
            for (int j = 0; j < 4; ++j) {
                int co = ct * 16 + q * 4 + j;
                if (co < DDEP) v[ct][j] = e[ct][j] / s;
            }
    }

    if (pok) {
#pragma unroll
        for (int ct = 0; ct < 4; ++ct)
#pragma unroll
            for (int j = 0; j < 4; ++j) {
                int co = (ct0 + ct) * 16 + q * 4 + j;
                if (co < NCH)
                    y[((size_t)n * NCH + co) * HW + px] = v[ct][j];
            }
    }
}

// ---------------- Stage 3: splat with LDS voxel cache + run-length dedup ---
__global__ __launch_bounds__(256) void k_splat2(const float* __restrict__ y,
                                                const float* __restrict__ rots,
                                                const float* __restrict__ trans,
                                                float* __restrict__ bev)
{
    __shared__ int vox[32 * DDEP];
    const int t  = threadIdx.x;
    const int p0 = blockIdx.x * 32;

    for (int k = t; k < 32 * DDEP; k += 256) {
        int pl = k / DDEP, d = k - pl * DDEP;
        int p = p0 + pl;
        int vx = -1;
        {
            int n = p / HW, hw = p - n * HW;
            int wi = hw % WW, hi = hw / WW;
            const float su = 1599.0f / 99.0f;
            const float sv = 899.0f / 55.0f;
            float u = __fmul_rn((float)wi, su);
            float v = __fmul_rn((float)hi, sv);
            const float* r = rots + n * 9;
            const float* tr = trans + n * 3;
            float dd  = 4.0f + (float)d;
            float pxv = __fmul_rn(u, dd);
            float pyv = __fmul_rn(v, dd);
            float gx = __fadd_rn(__fadd_rn(__fadd_rn(__fmul_rn(r[0], pxv), __fmul_rn(r[1], pyv)), __fmul_rn(r[2], dd)), tr[0]);
            float gy = __fadd_rn(__fadd_rn(__fadd_rn(__fmul_rn(r[3], pxv), __fmul_rn(r[4], pyv)), __fmul_rn(r[5], dd)), tr[1]);
            float gz = __fadd_rn(__fadd_rn(__fadd_rn(__fmul_rn(r[6], pxv), __fmul_rn(r[7], pyv)), __fmul_rn(r[8], dd)), tr[2]);
            int cx = (int)__fdiv_rn(__fadd_rn(gx, 50.0f), 3.0f);
            int cy = (int)__fdiv_rn(__fadd_rn(gy, 50.0f), 3.0f);
            int cz = (int)__fdiv_rn(__fadd_rn(gz, 5.0f), 3.0f);
            if (cx >= 0 && cx < NXG && cy >= 0 && cy < NYG && cz >= 0 && cz < NZG)
                vx = (cz * NYG + cy) * NXG + cx;
        }
        vox[k] = vx;
    }
    __syncthreads();

    const int g  = t >> 5;    // channel group 0..7
    const int pl = t & 31;
    const int p  = p0 + pl;
    int n = p / HW, hw = p - n * HW;
    const float* dbase = y + (size_t)n * NCH * HW + hw;
    const float* fbase = dbase + (size_t)DDEP * HW;
    float f[8];
#pragma unroll
    for (int j = 0; j < 8; ++j) f[j] = fbase[(size_t)(g * 8 + j) * HW];

    float a[8];
#pragma unroll
    for (int j = 0; j < 8; ++j) a[j] = 0.f;
    int cur = -1;
    for (int d = 0; d < DDEP; ++d) {
        int vx = vox[pl * DDEP + d];
        if (vx != cur) {
            if (cur >= 0) {
                float* vp = bev + (size_t)cur * CFEAT + g * 8;
#pragma unroll
                for (int j = 0; j < 8; ++j) atomicAdd(vp + j, a[j]);
            }
            cur = vx;
#pragma unroll
            for (int j = 0; j < 8; ++j) a[j] = 0.f;
        }
        if (vx >= 0) {
            float dval = dbase[(size_t)d * HW];
#pragma unroll
            for (int j = 0; j < 8; ++j) a[j] += __fmul_rn(dval, f[j]);
        }
    }
    if (cur >= 0) {
        float* vp = bev + (size_t)cur * CFEAT + g * 8;
#pragma unroll
        for (int j = 0; j < 8; ++j) atomicAdd(vp + j, a[j]);
    }
}

// ---------------- bev [vox][c] -> act0 [1225][128] single bf16_rn ----------
__global__ __launch_bounds__(256) void k_bev2act(const float* __restrict__ bev,
                                                 unsigned short* __restrict__ a0)
{
    int i = blockIdx.x * 256 + threadIdx.x;
    if (i >= NVOX * CFEAT) return;
    int vx = i >> 6, c = i & 63;
    int cz = vx / NPIXO, rem = vx - cz * NPIXO;
    int yy = rem / NXG, xx = rem - yy * NXG;
    int ch = c * 2 + cz;
    int pos = (yy + 1) * PADW + xx + 1;
    a0[pos * 128 + ch] = f2bf_rn(bev[i]);
}

// ---------------- MFMA 3x3 conv partials: W split hi/lo x act bf16 (2-term)-
// Single-barrier full-K staging: NSLOT=CHUNKS*4 slots/pos, XOR swizzle.
template<int CIN, int COUT, int SL>
__global__ __launch_bounds__(256) void k_conv_mfma(const unsigned short* __restrict__ act,
                                                   const unsigned short* __restrict__ wh,
                                                   const unsigned short* __restrict__ wl,
                                                   float* __restrict__ P)
{
    constexpr int CI_PER = CIN / SL;
    constexpr int CHUNKS = CI_PER / 32;       // 1 or 2
    constexpr int NSLOT  = CHUNKS * 4;
    constexpr int SMASK  = NSLOT - 1;
    constexpr int ROW    = NSLOT * 8;         // shorts per pos
    constexpr int NCOB = COUT / 64;
    constexpr int G    = NCOB * SL;
    constexpr int GX   = G / 8;
    constexpr int POSN = 140;
    __shared__ unsigned short bs[POSN * ROW]; // 8.96 or 17.9 KB
    const int t  = threadIdx.x;
    const int w  = t >> 6;
    const int l  = t & 63;
    const int lp = l & 15;
    const int q  = l >> 4;

    const int bid   = blockIdx.x;
    const int xcd   = bid & 7;
    const int slot  = bid >> 3;
    const int ytile = slot % 17;
    const int gon   = slot / 17;
    const int group = xcd * GX + gon;
    const int cobi  = group % NCOB;
    const int sl    = group / NCOB;

    const int y0  = ytile * 2;
    const int cob = cobi * 64 + w * 16;
    const int ci_base = sl * CI_PER;

    int  pos0[5];
    bool vld[5];
#pragma unroll
    for (int ct = 0; ct < 5; ++ct) {
        int tp = ct * 16 + lp;
        int r = tp / 33, c = tp - r * 33;
        bool v = (tp < 66) && (y0 + r < 33);
        vld[ct]  = v;
        pos0[ct] = v ? (r * 35 + c) : 0;
    }

    // stage all CI_PER act channels (single bf16), swizzled
    for (int i = t; i < POSN * NSLOT; i += 256) {
        int pos = i / NSLOT, s = i - pos * NSLOT;
        int gpos = y0 * 35 + pos;
        int sp = s ^ (pos & SMASK);
        uint4 val = make_uint4(0u, 0u, 0u, 0u);
        if (gpos < PADHW)
            val = *(const uint4*)&act[(size_t)gpos * CIN + ci_base + s * 8];
        *(uint4*)&bs[pos * ROW + sp * 8] = val;
    }
    __syncthreads();

    f32x4 acc[5];
#pragma unroll
    for (int ct = 0; ct < 5; ++ct) acc[ct] = (f32x4){0.f, 0.f, 0.f, 0.f};

#pragma unroll 3
    for (int dydx = 0; dydx < 9; ++dydx) {
        int dy = dydx / 3, dx = dydx - dy * 3;
        int off = dy * 35 + dx;
        bf16x8 Ah[CHUNKS], Al[CHUNKS];
#pragma unroll
        for (int c = 0; c < CHUNKS; ++c) {
            const size_t abase = (size_t)(((dydx * (COUT >> 4) + (cob >> 4)) * (CIN >> 5)
                                           + (ci_base >> 5) + c) * 64 + l) * 8;
            Ah[c] = *(const bf16x8*)&wh[abase];
            Al[c] = *(const bf16x8*)&wl[abase];
        }
#pragma unroll
        for (int ct = 0; ct < 5; ++ct) {
            int pos = pos0[ct] + off;
#pragma unroll
            for (int c = 0; c < CHUNKS; ++c) {
                int sph = (c * 4 + q) ^ (pos & SMASK);
                bf16x8 B = *(const bf16x8*)&bs[pos * ROW + sph * 8];
                acc[ct] = __builtin_amdgcn_mfma_f32_16x16x32_bf16(Ah[c], B, acc[ct], 0, 0, 0);
                acc[ct] = __builtin_amdgcn_mfma_f32_16x16x32_bf16(Al[c], B, acc[ct], 0, 0, 0);
            }
        }
    }

#pragma unroll
    for (int ct = 0; ct < 5; ++ct) {
        if (!vld[ct]) continue;
        int gp = y0 * 33 + ct * 16 + lp;
        float* dst = P + ((size_t)sl * NPIXO + gp) * COUT + cob + q * 4;
        *(f32x4*)dst = acc[ct];
    }
}

// ---------------- reduce slices + BN + ReLU -> next act (or final out) -----
template<int SL>
__global__ __launch_bounds__(256) void k_finish(const float* __restrict__ P,
                                                const float* __restrict__ bns,
                                                const float* __restrict__ bnb,
                                                const float* __restrict__ bnm,
                                                const float* __restrict__ bnv,
                                                unsigned short* __restrict__ oact,
                                                float* __restrict__ outf,
                                                int COUT)
{
    int i = blockIdx.x * 256 + threadIdx.x;
    if (i >= COUT * NPIXO) return;
    int co = i % COUT, p = i / COUT;
    float s = 0.f;
#pragma unroll
    for (int sl = 0; sl < SL; ++sl)
        s += P[((size_t)sl * NPIXO + p) * COUT + co];
    float sc = bns[co] / sqrtf(bnv[co] + 1e-5f);
    float bi = bnb[co] - bnm[co] * sc;
    float rv = fmaxf(fmaf(s, sc, bi), 0.f);
    if (outf) {
        outf[(size_t)co * NPIXO + p] = rv;
    } else {
        int yy = p / NXG, xx = p - yy * NXG;
        int pos = (yy + 1) * PADW + xx + 1;
        oact[(size_t)pos * COUT + co] = f2bf_rn(rv);
    }
}

extern "C" void kernel_launch(void* const* d_in, const int* in_sizes, int n_in,
                              void* d_out, int out_size, void* d_ws, size_t ws_size,
                              hipStream_t stream)
{
    const float* x     = (const float*)d_in[0];
    const float* rots  = (const float*)d_in[1];
    const float* trans = (const float*)d_in[2];
    const float* dnw   = (const float*)d_in[3];
    const float* dnb   = (const float*)d_in[4];
    const float* bw1   = (const float*)d_in[5];
    const float* bn1s  = (const float*)d_in[6];
    const float* bn1b  = (const float*)d_in[7];
    const float* bn1m  = (const float*)d_in[8];
    const float* bn1v  = (const float*)d_in[9];
    const float* bw2   = (const float*)d_in[10];
    const float* bn2s  = (const float*)d_in[11];
    const float* bn2b  = (const float*)d_in[12];
    const float* bn2m  = (const float*)d_in[13];
    const float* bn2v  = (const float*)d_in[14];
    const float* bw3   = (const float*)d_in[15];
    const float* bn3s  = (const float*)d_in[16];
    const float* bn3b  = (const float*)d_in[17];
    const float* bn3m  = (const float*)d_in[18];
    const float* bn3v  = (const float*)d_in[19];
    const float* bw4   = (const float*)d_in[20];
    const float* bn4s  = (const float*)d_in[21];
    const float* bn4b  = (const float*)d_in[22];
    const float* bn4m  = (const float*)d_in[23];
    const float* bn4v  = (const float*)d_in[24];

    float* ws  = (float*)d_ws;
    float* y   = ws + Y_OFF;
    float* bev = ws + BEV_OFF;
    float* P   = ws + P_OFF;
    unsigned short* wdh = (unsigned short*)(ws + WDH_OFF);
    unsigned short* wdl = (unsigned short*)(ws + WDL_OFF);
    unsigned short* w1h = (unsigned short*)(ws + W1H_OFF);
    unsigned short* w1l = (unsigned short*)(ws + W1L_OFF);
    unsigned short* w2h = (unsigned short*)(ws + W2H_OFF);
    unsigned short* w2l = (unsigned short*)(ws + W2L_OFF);
    unsigned short* w3h = (unsigned short*)(ws + W3H_OFF);
    unsigned short* w3l = (unsigned short*)(ws + W3L_OFF);
    unsigned short* w4h = (unsigned short*)(ws + W4H_OFF);
    unsigned short* w4l = (unsigned short*)(ws + W4L_OFF);
    unsigned short* a0  = (unsigned short*)(ws + A0_OFF);
    unsigned short* a1  = (unsigned short*)(ws + A1_OFF);
    unsigned short* a2  = (unsigned short*)(ws + A2_OFF);
    unsigned short* a3  = (unsigned short*)(ws + A3_OFF);
    float* out = (float*)d_out;

    // zero bev accumulator + act buffers (their padded borders must be 0)
    hipMemsetAsync(bev, 0, (size_t)(P_OFF - BEV_OFF) * sizeof(float), stream);

    k_wprep_all<<<16832, 256, 0, stream>>>(dnw, bw1, bw2, bw3, bw4,
                                           wdh, wdl, w1h, w1l, w2h, w2l,
                                           w3h, w3l, w4h, w4l);
    // depthnet + fused softmax (z-split: 1056 blocks)
    k_depthnet_fused<<<dim3(88, 6, 2), 256, 0, stream>>>(x, wdh, wdl, dnb, y);
    // splat with voxel dedup
    k_splat2<<<1050, 256, 0, stream>>>(y, rots, trans, bev);

    k_bev2act<<<(NVOX * CFEAT + 255) / 256, 256, 0, stream>>>(bev, a0);

    // conv1: 128 -> 128   (136 blocks)
    k_conv_mfma<128, 128, 4><<<136, 256, 0, stream>>>(a0, w1h, w1l, P);
    k_finish<4><<<(128 * NPIXO + 255) / 256, 256, 0, stream>>>(P, bn1s, bn1b, bn1m, bn1v, a1, nullptr, 128);
    // conv2: 128 -> 512   (544 blocks)
    k_conv_mfma<128, 512, 4><<<544, 256, 0, stream>>>(a1, w2h, w2l, P);
    k_finish<4><<<(512 * NPIXO + 255) / 256, 256, 0, stream>>>(P, bn2s, bn2b, bn2m, bn2v, a2, nullptr, 512);
    // conv3: 512 -> 512, SL=8  (1088 blocks)
    k_conv_mfma<512, 512, 8><<<1088, 256, 0, stream>>>(a2, w3h, w3l, P);
    k_finish<8><<<(512 * NPIXO + 255) / 256, 256, 0, stream>>>(P, bn3s, bn3b, bn3m, bn3v, a3, nullptr, 512);
    // conv4: 512 -> 256, SL=8  (544 blocks, final fp32 out [256][33][33])
    k_conv_mfma<512, 256, 8><<<544, 256, 0, stream>>>(a3, w4h, w4l, P);
    k_finish<8><<<(256 * NPIXO + 255) / 256, 256, 0, stream>>>(P, bn4s, bn4b, bn4m, bn4v, nullptr, out, 256);
}